// Round 10
// baseline (305.035 us; speedup 1.0000x reference)
//
#include <hip/hip_runtime.h>
#include <stdint.h>

#define SEQ 2048
// B=2, DIM=2048, NH=16, NKV=4, HD=128, qkv width = 2048+512+512 = 3072

typedef uint16_t u16;
typedef uint32_t u32;
typedef __attribute__((ext_vector_type(4))) float f32x4;
typedef __attribute__((ext_vector_type(8))) __bf16 bf16x8;
typedef __attribute__((ext_vector_type(4))) __bf16 bf16x4;

__device__ __forceinline__ u16 f2bf(float f) {
    u32 u = __float_as_uint(f);
    u += 0x7FFFu + ((u >> 16) & 1u);   // RNE
    return (u16)(u >> 16);
}
__device__ __forceinline__ float bf2f(u16 h) {
    return __uint_as_float(((u32)h) << 16);
}
// packed f32x2 -> bf16x2 (RNE), 1 VALU instr instead of ~8
__device__ __forceinline__ u32 cvt_pk_bf16(float lo, float hi) {
    u32 r;
    asm("v_cvt_pk_bf16_f32 %0, %1, %2" : "=v"(r) : "v"(lo), "v"(hi));
    return r;
}
__device__ __forceinline__ void async16(const void* g, void* l) {
    auto gp = (__attribute__((address_space(1))) void*)const_cast<void*>(g);
    auto lp = (__attribute__((address_space(3))) void*)l;
    __builtin_amdgcn_global_load_lds(gp, lp, 16, 0, 0);
}

// ------------- prep: x fp32->bf16 (blocks 0..8191) + all 4 weight transposes -------------
// blocks [8192, 10752): tconv over (bx, k0): bx in [0,80), by in [0,32).
__global__ __launch_bounds__(256) void prep(const float* __restrict__ x,
                                            const float* __restrict__ wq,
                                            const float* __restrict__ wk,
                                            const float* __restrict__ wv,
                                            const float* __restrict__ wo,
                                            u16* __restrict__ xb,
                                            u16* __restrict__ wqkvT,
                                            u16* __restrict__ woT) {
    const int bid = blockIdx.x;
    const int tid = threadIdx.x;
    if (bid < 8192) {
        int i = bid * 256 + tid;                 // one float4 per thread
        float4 v = ((const float4*)x)[i];
        ((uint2*)xb)[i] = make_uint2(cvt_pk_bf16(v.x, v.y), cvt_pk_bf16(v.z, v.w));
        return;
    }
    __shared__ float tile[64][65];
    const int tb = bid - 8192;
    const int bx = tb % 80, k0 = (tb / 80) * 64;
    const float* src; u16* dst; int N, n0;
    if (bx < 32)      { src = wq; dst = wqkvT;                        N = 2048; n0 = bx * 64; }
    else if (bx < 40) { src = wk; dst = wqkvT + (size_t)2048 * 2048;  N = 512;  n0 = (bx - 32) * 64; }
    else if (bx < 48) { src = wv; dst = wqkvT + (size_t)2560 * 2048;  N = 512;  n0 = (bx - 40) * 64; }
    else              { src = wo; dst = woT;                          N = 2048; n0 = (bx - 48) * 64; }
#pragma unroll
    for (int p = 0; p < 4; p++) {
        int r = p * 16 + (tid >> 4);
        int c = (tid & 15) * 4;
        float4 v = *(const float4*)&src[(size_t)(k0 + r) * N + n0 + c];
        tile[r][c] = v.x; tile[r][c+1] = v.y; tile[r][c+2] = v.z; tile[r][c+3] = v.w;
    }
    __syncthreads();
#pragma unroll
    for (int p = 0; p < 4; p++) {
        int n = p * 16 + (tid >> 4);
        int kq = (tid & 15) * 4;
        u32 lo = cvt_pk_bf16(tile[kq+0][n], tile[kq+1][n]);
        u32 hi = cvt_pk_bf16(tile[kq+2][n], tile[kq+3][n]);
        *(uint2*)&dst[(size_t)(n0 + n) * 2048 + k0 + kq] = make_uint2(lo, hi);
    }
}

// ---------------- bf16 GEMM, 128x128 tile, 4-slot ring, counted vmcnt ----------------
// r5 structure, ONE barrier per K-tile (mid-barrier removed; ledger: slot (kt+3)&3's
// previous readers consumed via lgkmcnt(0) before iter kt-1's end barrier -> the stage
// at iter kt cannot race them; current tile's reads protected by end-barrier vmcnt(8)).
template <bool FUSE>
__global__ __launch_bounds__(256, 2) void gemm128(const u16* __restrict__ A,
                                                  const u16* __restrict__ Bt,
                                                  void* __restrict__ Cv,
                                                  int N, int K, int nbx,
                                                  const float* __restrict__ cosp,
                                                  const float* __restrict__ sinp,
                                                  u16* __restrict__ vt) {
    __shared__ u16 lds[4 * 8192];             // 4 slots x (A 4096 + B 4096) u16

    // bijective XCD swizzle (m204)
    const int nwg = gridDim.x;
    const int q = nwg >> 3, r = nwg & 7;
    const int xcd = blockIdx.x & 7, lid = blockIdx.x >> 3;
    const int wg = (xcd < r ? xcd * (q + 1) : r * (q + 1) + (xcd - r) * q) + lid;
    const int by = wg / nbx, bx = wg - by * nbx;
    const int m0 = by * 128, n0 = bx * 128;

    const int tid = threadIdx.x;
    const int w = tid >> 6, l = tid & 63;
    const int lr = l & 15, quad = l >> 4;
    const int wm = (w >> 1) * 64, wn = (w & 1) * 64;
    const int cs = ((quad ^ (lr & 3) ^ ((lr >> 2) & 3)) & 3) * 8;

    const int sr = tid >> 2;
    const int sg = tid & 3;
    const int swz = (sr ^ (sr >> 2)) & 3;
    const u16* aS = A  + (size_t)(m0 + sr) * K + (sg ^ swz) * 8;
    const u16* bS = Bt + (size_t)(n0 + sr) * K + (sg ^ swz) * 8;
    u16* ldA = lds + tid * 8;
    u16* ldB = lds + 4096 + tid * 8;

    f32x4 acc[4][4] = {};
    const int nK = K >> 5;

    auto stage = [&](int kt) {
        u16* dA = ldA + (kt & 3) * 8192;
        u16* dB = ldB + (kt & 3) * 8192;
        const u16* sa = aS + (size_t)kt * 32;
        const u16* sb = bS + (size_t)kt * 32;
        async16(sa, dA);
        async16(sa + (size_t)64 * K, dA + 2048);   // swz(row+64) == swz(row)
        async16(sb, dB);
        async16(sb + (size_t)64 * K, dB + 2048);
    };

    stage(0); stage(1); stage(2);
    asm volatile("s_waitcnt vmcnt(8)" ::: "memory");   // tile 0 (4 oldest) landed
    __builtin_amdgcn_s_barrier();

    for (int kt = 0; kt < nK; ++kt) {
        const u16* As = lds + (kt & 3) * 8192;
        const u16* Bs = As + 4096;
        bf16x8 af[4], bfr[4];
#pragma unroll
        for (int i = 0; i < 4; i++)
            af[i] = *(const bf16x8*)&As[(wm + i * 16 + lr) * 32 + cs];
#pragma unroll
        for (int i = 0; i < 4; i++)
            bfr[i] = *(const bf16x8*)&Bs[(wn + i * 16 + lr) * 32 + cs];
        if (kt + 3 < nK) stage(kt + 3);            // slot (kt-1)&3: readers sealed last iter
        asm volatile("s_waitcnt lgkmcnt(0)" ::: "memory");
        __builtin_amdgcn_s_setprio(1);
#pragma unroll
        for (int mf = 0; mf < 4; mf++)
#pragma unroll
            for (int nf = 0; nf < 4; nf++)
                acc[mf][nf] = __builtin_amdgcn_mfma_f32_16x16x32_bf16(af[mf], bfr[nf], acc[mf][nf], 0, 0, 0);
        __builtin_amdgcn_s_setprio(0);
        if (kt < nK - 3)       asm volatile("s_waitcnt vmcnt(8)" ::: "memory");
        else if (kt == nK - 3) asm volatile("s_waitcnt vmcnt(4)" ::: "memory");
        else if (kt == nK - 2) asm volatile("s_waitcnt vmcnt(0)" ::: "memory");
        if (kt < nK - 1) __builtin_amdgcn_s_barrier();   // the ONLY barrier per K-tile
    }

    // ---------------- epilogue ----------------
    if constexpr (FUSE) {
        if (n0 >= 2560) {
            // V block: write transposed to vt[(b*4+kh)*128+d][token]
            const int bb = m0 >> 11;
#pragma unroll
            for (int mf = 0; mf < 4; mf++) {
                const int token0 = (m0 + wm + mf * 16 + quad * 4) & (SEQ - 1);
#pragma unroll
                for (int nf = 0; nf < 4; nf++) {
                    int dg = n0 - 2560 + wn + nf * 16 + lr;
                    int kh = dg >> 7, d = dg & 127;
                    u32 lo = cvt_pk_bf16(acc[mf][nf][0], acc[mf][nf][1]);
                    u32 hi = cvt_pk_bf16(acc[mf][nf][2], acc[mf][nf][3]);
                    *(uint2*)&vt[((size_t)((bb * 4 + kh) * 128 + d)) * SEQ + token0] = make_uint2(lo, hi);
                }
            }
        } else if (n0 >= 2048) {
            // K block: RoPE on f32 acc, then bf16 store
            const float sgn = (lr & 1) ? 1.0f : -1.0f;
#pragma unroll
            for (int mf = 0; mf < 4; mf++) {
#pragma unroll
                for (int nf = 0; nf < 4; nf++) {
                    int col = n0 + wn + nf * 16 + lr;
                    int ci = (col & 127) >> 1;
#pragma unroll
                    for (int rr = 0; rr < 4; rr++) {
                        size_t row = (size_t)(m0 + wm + mf * 16 + quad * 4 + rr);
                        int token = (int)row & (SEQ - 1);
                        float v = acc[mf][nf][rr];
                        float ppart = __shfl_xor(v, 1);
                        float c = cosp[token * 64 + ci];
                        float s = sinp[token * 64 + ci];
                        float ov = fmaf(sgn * ppart, s, v * c);
                        ((u16*)Cv)[row * (size_t)N + col] = f2bf(ov);
                    }
                }
            }
        } else {
#pragma unroll
            for (int mf = 0; mf < 4; mf++)
#pragma unroll
                for (int nf = 0; nf < 4; nf++)
#pragma unroll
                    for (int rr = 0; rr < 4; rr++) {
                        size_t row = (size_t)(m0 + wm + mf * 16 + quad * 4 + rr);
                        size_t col = (size_t)(n0 + wn + nf * 16 + lr);
                        ((u16*)Cv)[row * (size_t)N + col] = f2bf(acc[mf][nf][rr]);
                    }
        }
    } else {
#pragma unroll
        for (int mf = 0; mf < 4; mf++)
#pragma unroll
            for (int nf = 0; nf < 4; nf++)
#pragma unroll
                for (int rr = 0; rr < 4; rr++) {
                    size_t row = (size_t)(m0 + wm + mf * 16 + quad * 4 + rr);
                    size_t col = (size_t)(n0 + wn + nf * 16 + lr);
                    ((float*)Cv)[row * (size_t)N + col] = acc[mf][nf][rr];
                }
    }
}

// ---------------- causal GQA flash attention (r8-verified: V-dbuf, 2 barriers/iter) ----------------
__global__ __launch_bounds__(512, 2) void flash_attn(const u16* __restrict__ qkv,
                                                     const u16* __restrict__ vt,
                                                     const float* __restrict__ cosp,
                                                     const float* __restrict__ sinp,
                                                     u16* __restrict__ ob) {
    __shared__ u16 sh[81920];                    // 160 KB
    const int bidx = blockIdx.x;
    const int xcd   = bidx & 7;
    const int inner = bidx >> 3;
    const int b  = xcd >> 2, kh = xcd & 3;       // (b,kh) constant per XCD
    const int h  = kh * 4 + (inner & 3);
    const int a  = inner >> 2;
    const int tid = threadIdx.x;
    const int w = tid >> 6, lane = tid & 63;
    const int grp = w >> 2, wl = w & 3;
    const int lr = lane & 15, quad = lane >> 4;
    const float qscale = 0.088388347762f * 1.4426950408889634f;   // (1/sqrt(128))*log2(e)

    u16* base_g = sh + grp * 32768;              // kb0 | kb1 | vb0 | vb1 (8192 u16 each)
    u16* lPw = sh + 65536 + w * 2048;            // 32 rows x 64 per wave

    const int tidg = tid & 255;
    const int krow = tidg >> 4;
    const int kchunk = (tidg & 15) ^ krow;
    const int vrow = tidg >> 3;
    const int vchunk = (tidg & 7) ^ (vrow & 7);
    const u16* kRow = qkv + (size_t)b * SEQ * 3072 + 2048 + kh * 128
                    + (size_t)krow * 3072 + kchunk * 8;
    const u16* vRow = vt + (size_t)(b * 4 + kh) * 128 * SEQ
                    + (size_t)vrow * SEQ + vchunk * 8;

    auto stageK = [&](int kt, int buf) {
        u16* d = base_g + buf * 8192 + tidg * 8;
#pragma unroll
        for (int i = 0; i < 4; i++)
            async16(kRow + (size_t)(kt * 64 + i * 16) * 3072, d + i * 2048);
    };
    auto stageV = [&](int kt, int buf) {
        u16* d = base_g + 16384 + buf * 8192 + tidg * 8;
#pragma unroll
        for (int i = 0; i < 4; i++)
            async16(vRow + (size_t)(i * 32) * SEQ + kt * 64, d + i * 2048);
    };

    float* mO = (float*)sh;                      // merge: 128x128 f32 (over grp0 K/V, dead then)
    float* mM = (float*)(sh + 65536);            // merge: 128x(m,l) f32 (over P region, dead then)

    for (int p = 0; p < 2; p++) {
        const int qt = p ? (7 - a) : (8 + a);
        const int niters = p ? (8 - a) : (9 + a);
        const int kt0 = grp * niters;

        stageK(kt0, 0);                          // prologue prefetch hides under Q-RoPE
        stageV(kt0, 0);

        // Q fragments (A-layout) with fused RoPE + scale*log2e
        bf16x8 qf[2][4];
#pragma unroll
        for (int qi = 0; qi < 2; qi++) {
            const int token = qt * 128 + wl * 32 + qi * 16 + lr;
            const u16* qb = qkv + (size_t)(b * SEQ + token) * 3072 + h * 128;
#pragma unroll
            for (int kk = 0; kk < 4; kk++) {
                uint4 raw = *(const uint4*)(qb + kk * 32 + quad * 8);
                u32 rw[4] = {raw.x, raw.y, raw.z, raw.w};
                union { u32 u[4]; bf16x8 v; } fr;
#pragma unroll
                for (int pp = 0; pp < 4; pp++) {
                    int ci = kk * 16 + quad * 4 + pp;
                    float cv = cosp[token * 64 + ci];
                    float sv = sinp[token * 64 + ci];
                    float tr = bf2f((u16)(rw[pp] & 0xFFFFu));
                    float ti = bf2f((u16)(rw[pp] >> 16));
                    fr.u[pp] = cvt_pk_bf16((tr * cv - ti * sv) * qscale,
                                           (tr * sv + ti * cv) * qscale);
                }
                qf[qi][kk] = fr.v;
            }
        }

        f32x4 o[2][8] = {};
        float m_st[2] = {-1e30f, -1e30f};
        float l_st[2] = {0.f, 0.f};
        const int qg = qt * 128 + wl * 32 + lr;

        for (int t = 0; t < niters; t++) {
            const int kt = kt0 + t;
            const int bu = t & 1;
            if (t + 1 < niters) {
                stageK(kt + 1, bu ^ 1);
                asm volatile("s_waitcnt vmcnt(8)" ::: "memory");   // waits exactly K(t)
            } else {
                asm volatile("s_waitcnt vmcnt(4)" ::: "memory");   // waits K(t), leaves V(t)
            }
            asm volatile("s_barrier" ::: "memory");                // also seals PV(t-1) reads

            const u16* kcur = base_g + bu * 8192;
            f32x4 sc[2][4] = {};
            __builtin_amdgcn_s_setprio(1);
#pragma unroll
            for (int nf = 0; nf < 4; nf++) {
#pragma unroll
                for (int kk = 0; kk < 4; kk++) {
                    bf16x8 ak = *(const bf16x8*)&kcur[(nf * 16 + lr) * 128 + (((kk * 4 + quad) ^ lr) * 8)];
                    sc[0][nf] = __builtin_amdgcn_mfma_f32_16x16x32_bf16(ak, qf[0][kk], sc[0][nf], 0, 0, 0);
                    sc[1][nf] = __builtin_amdgcn_mfma_f32_16x16x32_bf16(ak, qf[1][kk], sc[1][nf], 0, 0, 0);
                }
            }
            __builtin_amdgcn_s_setprio(0);

            const int kb = kt * 64 + quad * 4;
            const int kmax = kt * 64 + 63;
#pragma unroll
            for (int qi = 0; qi < 2; qi++) {
                float ps[4][4];
                float tm[4];
                const int qrow_g = qg + qi * 16;
                if (kmax > qt * 128 + wl * 32 + qi * 16) {     // wave-uniform: crosses diagonal
#pragma unroll
                    for (int nf = 0; nf < 4; nf++) {
                        tm[nf] = -1e30f;
#pragma unroll
                        for (int r = 0; r < 4; r++) {
                            float v = sc[qi][nf][r];
                            if ((kb + nf * 16 + r) > qrow_g) v = -1e30f;
                            ps[nf][r] = v;
                            tm[nf] = fmaxf(tm[nf], v);
                        }
                    }
                } else {
#pragma unroll
                    for (int nf = 0; nf < 4; nf++) {
                        tm[nf] = -1e30f;
#pragma unroll
                        for (int r = 0; r < 4; r++) {
                            float v = sc[qi][nf][r];
                            ps[nf][r] = v;
                            tm[nf] = fmaxf(tm[nf], v);
                        }
                    }
                }
                float tmax = fmaxf(fmaxf(tm[0], tm[1]), fmaxf(tm[2], tm[3]));
                tmax = fmaxf(tmax, __shfl_xor(tmax, 16));
                tmax = fmaxf(tmax, __shfl_xor(tmax, 32));
                const float mprev = m_st[qi];
                if (!__all(tmax - mprev <= 8.0f)) {            // T13 defer-max
                    float mnew = fmaxf(mprev, tmax);
                    float alpha = exp2f(mprev - mnew);
                    l_st[qi] *= alpha;
                    m_st[qi] = mnew;
#pragma unroll
                    for (int r = 0; r < 4; r++) {
                        float ar = __shfl(alpha, quad * 4 + r, 16);
#pragma unroll
                        for (int nd = 0; nd < 8; nd++) o[qi][nd][r] *= ar;
                    }
                }
                const float mcur = m_st[qi];
                float rs[4];
#pragma unroll
                for (int nf = 0; nf < 4; nf++) {
                    rs[nf] = 0.f;
#pragma unroll
                    for (int r = 0; r < 4; r++) {
                        float e = exp2f(ps[nf][r] - mcur);
                        ps[nf][r] = e;
                        rs[nf] += e;
                    }
                }
                float rsum = (rs[0] + rs[1]) + (rs[2] + rs[3]);
                rsum += __shfl_xor(rsum, 16);
                rsum += __shfl_xor(rsum, 32);
                l_st[qi] += rsum;
                const int qrow = qi * 16 + lr;
#pragma unroll
                for (int nf = 0; nf < 4; nf++) {
                    u32 lo = cvt_pk_bf16(ps[nf][0], ps[nf][1]);
                    u32 hi = cvt_pk_bf16(ps[nf][2], ps[nf][3]);
                    int c = (nf * 4 + quad) ^ lr;
                    *(uint2*)&lPw[qrow * 64 + c * 4] = make_uint2(lo, hi);
                }
            }

            if (t + 1 < niters) asm volatile("s_waitcnt vmcnt(4)" ::: "memory");  // waits V(t)
            else                asm volatile("s_waitcnt vmcnt(0)" ::: "memory");
            asm volatile("s_barrier" ::: "memory");

            if (t + 1 < niters) stageV(kt + 1, bu ^ 1);        // overlaps PV(t) + QK(t+1)

            const u16* vcur = base_g + 16384 + bu * 8192;
            __builtin_amdgcn_s_setprio(1);
#pragma unroll
            for (int kf = 0; kf < 2; kf++) {
                bf16x8 pa[2];
#pragma unroll
                for (int qi = 0; qi < 2; qi++) {
                    int c0 = (kf * 8 + quad * 2) ^ lr;
                    int c1 = (kf * 8 + quad * 2 + 1) ^ lr;
                    bf16x4 p0 = *(const bf16x4*)&lPw[(qi * 16 + lr) * 64 + c0 * 4];
                    bf16x4 p1 = *(const bf16x4*)&lPw[(qi * 16 + lr) * 64 + c1 * 4];
                    pa[qi] = __builtin_shufflevector(p0, p1, 0, 1, 2, 3, 4, 5, 6, 7);
                }
#pragma unroll
                for (int nd = 0; nd < 8; nd++) {
                    bf16x8 vv = *(const bf16x8*)&vcur[(nd * 16 + lr) * 64 + (((kf * 4 + quad) ^ (lr & 7)) * 8)];
                    o[0][nd] = __builtin_amdgcn_mfma_f32_16x16x32_bf16(pa[0], vv, o[0][nd], 0, 0, 0);
                    o[1][nd] = __builtin_amdgcn_mfma_f32_16x16x32_bf16(pa[1], vv, o[1][nd], 0, 0, 0);
                }
            }
            __builtin_amdgcn_s_setprio(0);
            // no third barrier: next iter's first barrier seals PV reads
        }

        // ---- in-block merge of the two K-halves ----
        __syncthreads();
        if (grp == 1) {
#pragma unroll
            for (int qi = 0; qi < 2; qi++) {
#pragma unroll
                for (int r = 0; r < 4; r++) {
                    int row = wl * 32 + qi * 16 + quad * 4 + r;
#pragma unroll
                    for (int nd = 0; nd < 8; nd++)
                        mO[row * 128 + nd * 16 + lr] = o[qi][nd][r];
                }
                if (quad == 0) {
                    int rowl = wl * 32 + qi * 16 + lr;
                    mM[rowl * 2]     = m_st[qi];
                    mM[rowl * 2 + 1] = l_st[qi];
                }
            }
        }
        __syncthreads();
        if (grp == 0) {
#pragma unroll
            for (int qi = 0; qi < 2; qi++) {
                int rowl = wl * 32 + qi * 16 + lr;
                float m1 = mM[rowl * 2], l1 = mM[rowl * 2 + 1];
                float M  = fmaxf(m_st[qi], m1);
                float a0 = exp2f(m_st[qi] - M);
                float a1 = exp2f(m1 - M);
                float li = 1.0f / (l_st[qi] * a0 + l1 * a1);
                u16* obase = ob + (size_t)(b * SEQ + qt * 128 + wl * 32 + qi * 16) * 2048 + h * 128;
#pragma unroll
                for (int r = 0; r < 4; r++) {
                    float a0b = __shfl(a0, quad * 4 + r, 16);
                    float a1b = __shfl(a1, quad * 4 + r, 16);
                    float lib = __shfl(li, quad * 4 + r, 16);
                    int row = wl * 32 + qi * 16 + quad * 4 + r;
#pragma unroll
                    for (int nd = 0; nd < 8; nd++) {
                        float val = (o[qi][nd][r] * a0b + mO[row * 128 + nd * 16 + lr] * a1b) * lib;
                        obase[(quad * 4 + r) * 2048 + nd * 16 + lr] = f2bf(val);
                    }
                }
            }
        }
        __syncthreads();   // merge reads done before next phase restages K/V regions
    }
}

extern "C" void kernel_launch(void* const* d_in, const int* in_sizes, int n_in,
                              void* d_out, int out_size, void* d_ws, size_t ws_size,
                              hipStream_t stream) {
    (void)in_sizes; (void)n_in; (void)out_size; (void)ws_size;
    const float* x    = (const float*)d_in[0];
    const float* cosp = (const float*)d_in[1];
    const float* sinp = (const float*)d_in[2];
    const float* wq   = (const float*)d_in[3];
    const float* wk   = (const float*)d_in[4];
    const float* wv   = (const float*)d_in[5];
    const float* wo   = (const float*)d_in[6];
    float* out = (float*)d_out;

    char* ws = (char*)d_ws;
    u16* xb    = (u16*)(ws);                               // 16 MB (reused as ob)
    u16* qkvb  = (u16*)(ws + (size_t)16 * 1024 * 1024);    // 24 MB
    u16* wqkvT = (u16*)(ws + (size_t)40 * 1024 * 1024);    // 12 MB
    u16* woT   = (u16*)(ws + (size_t)52 * 1024 * 1024);    //  8 MB
    u16* vtb   = (u16*)(ws + (size_t)60 * 1024 * 1024);    //  4 MB
    u16* ob    = xb;                                       // alias: xb dead after QKV GEMM

    prep<<<10752, 256, 0, stream>>>(x, wq, wk, wv, wo, xb, wqkvT, woT);
    // QKV GEMM with fused K-RoPE + V-transpose epilogue; grid 768 = 3x256 CUs
    gemm128<true><<<768, 256, 0, stream>>>(xb, wqkvT, (void*)qkvb, 3072, 2048, 24,
                                           cosp, sinp, vtb);
    flash_attn<<<256, 512, 0, stream>>>(qkvb, vtb, cosp, sinp, ob);
    // out-proj; grid 512 = 2x256 CUs
    gemm128<false><<<512, 256, 0, stream>>>(ob, woT, (void*)out, 2048, 2048, 16,
                                            nullptr, nullptr, nullptr);
}

// Round 11
// 304.466 us; speedup vs baseline: 1.0019x; 1.0019x over previous
//
#include <hip/hip_runtime.h>
#include <stdint.h>

#define SEQ 2048
// B=2, DIM=2048, NH=16, NKV=4, HD=128, qkv width = 2048+512+512 = 3072

typedef uint16_t u16;
typedef uint32_t u32;
typedef __attribute__((ext_vector_type(4))) float f32x4;
typedef __attribute__((ext_vector_type(8))) __bf16 bf16x8;
typedef __attribute__((ext_vector_type(4))) __bf16 bf16x4;

__device__ __forceinline__ u16 f2bf(float f) {
    u32 u = __float_as_uint(f);
    u += 0x7FFFu + ((u >> 16) & 1u);   // RNE
    return (u16)(u >> 16);
}
__device__ __forceinline__ float bf2f(u16 h) {
    return __uint_as_float(((u32)h) << 16);
}
// packed f32x2 -> bf16x2 (RNE), 1 VALU instr instead of ~8
__device__ __forceinline__ u32 cvt_pk_bf16(float lo, float hi) {
    u32 r;
    asm("v_cvt_pk_bf16_f32 %0, %1, %2" : "=v"(r) : "v"(lo), "v"(hi));
    return r;
}
__device__ __forceinline__ void async16(const void* g, void* l) {
    auto gp = (__attribute__((address_space(1))) void*)const_cast<void*>(g);
    auto lp = (__attribute__((address_space(3))) void*)l;
    __builtin_amdgcn_global_load_lds(gp, lp, 16, 0, 0);
}

// ------------- prep: x fp32->bf16 (blocks 0..8191) + all 4 weight transposes -------------
// blocks [8192, 10752): tconv over (bx, k0): bx in [0,80), by in [0,32).
__global__ __launch_bounds__(256) void prep(const float* __restrict__ x,
                                            const float* __restrict__ wq,
                                            const float* __restrict__ wk,
                                            const float* __restrict__ wv,
                                            const float* __restrict__ wo,
                                            u16* __restrict__ xb,
                                            u16* __restrict__ wqkvT,
                                            u16* __restrict__ woT) {
    const int bid = blockIdx.x;
    const int tid = threadIdx.x;
    if (bid < 8192) {
        int i = bid * 256 + tid;                 // one float4 per thread
        float4 v = ((const float4*)x)[i];
        ((uint2*)xb)[i] = make_uint2(cvt_pk_bf16(v.x, v.y), cvt_pk_bf16(v.z, v.w));
        return;
    }
    __shared__ float tile[64][65];
    const int tb = bid - 8192;
    const int bx = tb % 80, k0 = (tb / 80) * 64;
    const float* src; u16* dst; int N, n0;
    if (bx < 32)      { src = wq; dst = wqkvT;                        N = 2048; n0 = bx * 64; }
    else if (bx < 40) { src = wk; dst = wqkvT + (size_t)2048 * 2048;  N = 512;  n0 = (bx - 32) * 64; }
    else if (bx < 48) { src = wv; dst = wqkvT + (size_t)2560 * 2048;  N = 512;  n0 = (bx - 40) * 64; }
    else              { src = wo; dst = woT;                          N = 2048; n0 = (bx - 48) * 64; }
#pragma unroll
    for (int p = 0; p < 4; p++) {
        int r = p * 16 + (tid >> 4);
        int c = (tid & 15) * 4;
        float4 v = *(const float4*)&src[(size_t)(k0 + r) * N + n0 + c];
        tile[r][c] = v.x; tile[r][c+1] = v.y; tile[r][c+2] = v.z; tile[r][c+3] = v.w;
    }
    __syncthreads();
#pragma unroll
    for (int p = 0; p < 4; p++) {
        int n = p * 16 + (tid >> 4);
        int kq = (tid & 15) * 4;
        u32 lo = cvt_pk_bf16(tile[kq+0][n], tile[kq+1][n]);
        u32 hi = cvt_pk_bf16(tile[kq+2][n], tile[kq+3][n]);
        *(uint2*)&dst[(size_t)(n0 + n) * 2048 + k0 + kq] = make_uint2(lo, hi);
    }
}

// ---------------- bf16 GEMM, 128x128 tile, 4-slot ring, counted vmcnt ----------------
// r5 structure, ONE barrier per K-tile (r9/r10: measured == 2-barrier within noise; kept).
template <bool FUSE>
__global__ __launch_bounds__(256, 2) void gemm128(const u16* __restrict__ A,
                                                  const u16* __restrict__ Bt,
                                                  void* __restrict__ Cv,
                                                  int N, int K, int nbx,
                                                  const float* __restrict__ cosp,
                                                  const float* __restrict__ sinp,
                                                  u16* __restrict__ vt) {
    __shared__ u16 lds[4 * 8192];             // 4 slots x (A 4096 + B 4096) u16

    // bijective XCD swizzle (m204)
    const int nwg = gridDim.x;
    const int q = nwg >> 3, r = nwg & 7;
    const int xcd = blockIdx.x & 7, lid = blockIdx.x >> 3;
    const int wg = (xcd < r ? xcd * (q + 1) : r * (q + 1) + (xcd - r) * q) + lid;
    const int by = wg / nbx, bx = wg - by * nbx;
    const int m0 = by * 128, n0 = bx * 128;

    const int tid = threadIdx.x;
    const int w = tid >> 6, l = tid & 63;
    const int lr = l & 15, quad = l >> 4;
    const int wm = (w >> 1) * 64, wn = (w & 1) * 64;
    const int cs = ((quad ^ (lr & 3) ^ ((lr >> 2) & 3)) & 3) * 8;

    const int sr = tid >> 2;
    const int sg = tid & 3;
    const int swz = (sr ^ (sr >> 2)) & 3;
    const u16* aS = A  + (size_t)(m0 + sr) * K + (sg ^ swz) * 8;
    const u16* bS = Bt + (size_t)(n0 + sr) * K + (sg ^ swz) * 8;
    u16* ldA = lds + tid * 8;
    u16* ldB = lds + 4096 + tid * 8;

    f32x4 acc[4][4] = {};
    const int nK = K >> 5;

    auto stage = [&](int kt) {
        u16* dA = ldA + (kt & 3) * 8192;
        u16* dB = ldB + (kt & 3) * 8192;
        const u16* sa = aS + (size_t)kt * 32;
        const u16* sb = bS + (size_t)kt * 32;
        async16(sa, dA);
        async16(sa + (size_t)64 * K, dA + 2048);   // swz(row+64) == swz(row)
        async16(sb, dB);
        async16(sb + (size_t)64 * K, dB + 2048);
    };

    stage(0); stage(1); stage(2);
    asm volatile("s_waitcnt vmcnt(8)" ::: "memory");   // tile 0 (4 oldest) landed
    __builtin_amdgcn_s_barrier();

    for (int kt = 0; kt < nK; ++kt) {
        const u16* As = lds + (kt & 3) * 8192;
        const u16* Bs = As + 4096;
        bf16x8 af[4], bfr[4];
#pragma unroll
        for (int i = 0; i < 4; i++)
            af[i] = *(const bf16x8*)&As[(wm + i * 16 + lr) * 32 + cs];
#pragma unroll
        for (int i = 0; i < 4; i++)
            bfr[i] = *(const bf16x8*)&Bs[(wn + i * 16 + lr) * 32 + cs];
        if (kt + 3 < nK) stage(kt + 3);            // slot (kt-1)&3: readers sealed last iter
        asm volatile("s_waitcnt lgkmcnt(0)" ::: "memory");
        __builtin_amdgcn_s_setprio(1);
#pragma unroll
        for (int mf = 0; mf < 4; mf++)
#pragma unroll
            for (int nf = 0; nf < 4; nf++)
                acc[mf][nf] = __builtin_amdgcn_mfma_f32_16x16x32_bf16(af[mf], bfr[nf], acc[mf][nf], 0, 0, 0);
        __builtin_amdgcn_s_setprio(0);
        if (kt < nK - 3)       asm volatile("s_waitcnt vmcnt(8)" ::: "memory");
        else if (kt == nK - 3) asm volatile("s_waitcnt vmcnt(4)" ::: "memory");
        else if (kt == nK - 2) asm volatile("s_waitcnt vmcnt(0)" ::: "memory");
        if (kt < nK - 1) __builtin_amdgcn_s_barrier();   // the ONLY barrier per K-tile
    }

    // ---------------- epilogue ----------------
    if constexpr (FUSE) {
        if (n0 >= 2560) {
            // V block: write transposed to vt[(b*4+kh)*128+d][token]
            const int bb = m0 >> 11;
#pragma unroll
            for (int mf = 0; mf < 4; mf++) {
                const int token0 = (m0 + wm + mf * 16 + quad * 4) & (SEQ - 1);
#pragma unroll
                for (int nf = 0; nf < 4; nf++) {
                    int dg = n0 - 2560 + wn + nf * 16 + lr;
                    int kh = dg >> 7, d = dg & 127;
                    u32 lo = cvt_pk_bf16(acc[mf][nf][0], acc[mf][nf][1]);
                    u32 hi = cvt_pk_bf16(acc[mf][nf][2], acc[mf][nf][3]);
                    *(uint2*)&vt[((size_t)((bb * 4 + kh) * 128 + d)) * SEQ + token0] = make_uint2(lo, hi);
                }
            }
        } else if (n0 >= 2048) {
            // K block: RoPE on f32 acc, then bf16 store
            const float sgn = (lr & 1) ? 1.0f : -1.0f;
#pragma unroll
            for (int mf = 0; mf < 4; mf++) {
#pragma unroll
                for (int nf = 0; nf < 4; nf++) {
                    int col = n0 + wn + nf * 16 + lr;
                    int ci = (col & 127) >> 1;
#pragma unroll
                    for (int rr = 0; rr < 4; rr++) {
                        size_t row = (size_t)(m0 + wm + mf * 16 + quad * 4 + rr);
                        int token = (int)row & (SEQ - 1);
                        float v = acc[mf][nf][rr];
                        float ppart = __shfl_xor(v, 1);
                        float c = cosp[token * 64 + ci];
                        float s = sinp[token * 64 + ci];
                        float ov = fmaf(sgn * ppart, s, v * c);
                        ((u16*)Cv)[row * (size_t)N + col] = f2bf(ov);
                    }
                }
            }
        } else {
#pragma unroll
            for (int mf = 0; mf < 4; mf++)
#pragma unroll
                for (int nf = 0; nf < 4; nf++)
#pragma unroll
                    for (int rr = 0; rr < 4; rr++) {
                        size_t row = (size_t)(m0 + wm + mf * 16 + quad * 4 + rr);
                        size_t col = (size_t)(n0 + wn + nf * 16 + lr);
                        ((u16*)Cv)[row * (size_t)N + col] = f2bf(acc[mf][nf][rr]);
                    }
        }
    } else {
#pragma unroll
        for (int mf = 0; mf < 4; mf++)
#pragma unroll
            for (int nf = 0; nf < 4; nf++)
#pragma unroll
                for (int rr = 0; rr < 4; rr++) {
                    size_t row = (size_t)(m0 + wm + mf * 16 + quad * 4 + rr);
                    size_t col = (size_t)(n0 + wn + nf * 16 + lr);
                    ((float*)Cv)[row * (size_t)N + col] = acc[mf][nf][rr];
                }
    }
}

// ---------------- causal GQA flash attention ----------------
// r8 structure (V-dbuf, 2 barriers/iter) + r11 latency-hiding:
//  (1) stageV(t+1) issued right after barrier1 (vb[bu^1]'s last readers, PV(t-1),
//      provably complete at barrier1: their ds_reads were lgkm-consumed pre-barrier).
//      V-wait ledger: in-flight after V(t) = K(t+1)+V(t+1) = 8 -> vmcnt(8); tail 0.
//  (2) pa ds_reads (per-wave P region, same-wave ordering) hoisted BEFORE the
//      V-wait + barrier2 so the barrier-wait absorbs their lgkm latency.
__global__ __launch_bounds__(512, 2) void flash_attn(const u16* __restrict__ qkv,
                                                     const u16* __restrict__ vt,
                                                     const float* __restrict__ cosp,
                                                     const float* __restrict__ sinp,
                                                     u16* __restrict__ ob) {
    __shared__ u16 sh[81920];                    // 160 KB
    const int bidx = blockIdx.x;
    const int xcd   = bidx & 7;
    const int inner = bidx >> 3;
    const int b  = xcd >> 2, kh = xcd & 3;       // (b,kh) constant per XCD
    const int h  = kh * 4 + (inner & 3);
    const int a  = inner >> 2;
    const int tid = threadIdx.x;
    const int w = tid >> 6, lane = tid & 63;
    const int grp = w >> 2, wl = w & 3;
    const int lr = lane & 15, quad = lane >> 4;
    const float qscale = 0.088388347762f * 1.4426950408889634f;   // (1/sqrt(128))*log2(e)

    u16* base_g = sh + grp * 32768;              // kb0 | kb1 | vb0 | vb1 (8192 u16 each)
    u16* lPw = sh + 65536 + w * 2048;            // 32 rows x 64 per wave

    const int tidg = tid & 255;
    const int krow = tidg >> 4;
    const int kchunk = (tidg & 15) ^ krow;
    const int vrow = tidg >> 3;
    const int vchunk = (tidg & 7) ^ (vrow & 7);
    const u16* kRow = qkv + (size_t)b * SEQ * 3072 + 2048 + kh * 128
                    + (size_t)krow * 3072 + kchunk * 8;
    const u16* vRow = vt + (size_t)(b * 4 + kh) * 128 * SEQ
                    + (size_t)vrow * SEQ + vchunk * 8;

    auto stageK = [&](int kt, int buf) {
        u16* d = base_g + buf * 8192 + tidg * 8;
#pragma unroll
        for (int i = 0; i < 4; i++)
            async16(kRow + (size_t)(kt * 64 + i * 16) * 3072, d + i * 2048);
    };
    auto stageV = [&](int kt, int buf) {
        u16* d = base_g + 16384 + buf * 8192 + tidg * 8;
#pragma unroll
        for (int i = 0; i < 4; i++)
            async16(vRow + (size_t)(i * 32) * SEQ + kt * 64, d + i * 2048);
    };

    float* mO = (float*)sh;                      // merge: 128x128 f32 (over grp0 K/V, dead then)
    float* mM = (float*)(sh + 65536);            // merge: 128x(m,l) f32 (over P region, dead then)

    for (int p = 0; p < 2; p++) {
        const int qt = p ? (7 - a) : (8 + a);
        const int niters = p ? (8 - a) : (9 + a);
        const int kt0 = grp * niters;

        stageK(kt0, 0);                          // prologue prefetch hides under Q-RoPE
        stageV(kt0, 0);

        // Q fragments (A-layout) with fused RoPE + scale*log2e
        bf16x8 qf[2][4];
#pragma unroll
        for (int qi = 0; qi < 2; qi++) {
            const int token = qt * 128 + wl * 32 + qi * 16 + lr;
            const u16* qb = qkv + (size_t)(b * SEQ + token) * 3072 + h * 128;
#pragma unroll
            for (int kk = 0; kk < 4; kk++) {
                uint4 raw = *(const uint4*)(qb + kk * 32 + quad * 8);
                u32 rw[4] = {raw.x, raw.y, raw.z, raw.w};
                union { u32 u[4]; bf16x8 v; } fr;
#pragma unroll
                for (int pp = 0; pp < 4; pp++) {
                    int ci = kk * 16 + quad * 4 + pp;
                    float cv = cosp[token * 64 + ci];
                    float sv = sinp[token * 64 + ci];
                    float tr = bf2f((u16)(rw[pp] & 0xFFFFu));
                    float ti = bf2f((u16)(rw[pp] >> 16));
                    fr.u[pp] = cvt_pk_bf16((tr * cv - ti * sv) * qscale,
                                           (tr * sv + ti * cv) * qscale);
                }
                qf[qi][kk] = fr.v;
            }
        }

        f32x4 o[2][8] = {};
        float m_st[2] = {-1e30f, -1e30f};
        float l_st[2] = {0.f, 0.f};
        const int qg = qt * 128 + wl * 32 + lr;

        for (int t = 0; t < niters; t++) {
            const int kt = kt0 + t;
            const int bu = t & 1;
            if (t + 1 < niters) {
                stageK(kt + 1, bu ^ 1);
                asm volatile("s_waitcnt vmcnt(8)" ::: "memory");   // waits exactly K(t)
            } else {
                asm volatile("s_waitcnt vmcnt(4)" ::: "memory");   // waits K(t), leaves V(t)
            }
            asm volatile("s_barrier" ::: "memory");                // also seals PV(t-1) reads

            // (1) issue V(t+1) NOW: vb[bu^1]'s last readers (PV(t-1)) sealed by the
            // barrier above; latency hides under QK + softmax + PV.
            if (t + 1 < niters) stageV(kt + 1, bu ^ 1);

            const u16* kcur = base_g + bu * 8192;
            f32x4 sc[2][4] = {};
            __builtin_amdgcn_s_setprio(1);
#pragma unroll
            for (int nf = 0; nf < 4; nf++) {
#pragma unroll
                for (int kk = 0; kk < 4; kk++) {
                    bf16x8 ak = *(const bf16x8*)&kcur[(nf * 16 + lr) * 128 + (((kk * 4 + quad) ^ lr) * 8)];
                    sc[0][nf] = __builtin_amdgcn_mfma_f32_16x16x32_bf16(ak, qf[0][kk], sc[0][nf], 0, 0, 0);
                    sc[1][nf] = __builtin_amdgcn_mfma_f32_16x16x32_bf16(ak, qf[1][kk], sc[1][nf], 0, 0, 0);
                }
            }
            __builtin_amdgcn_s_setprio(0);

            const int kb = kt * 64 + quad * 4;
            const int kmax = kt * 64 + 63;
#pragma unroll
            for (int qi = 0; qi < 2; qi++) {
                float ps[4][4];
                float tm[4];
                const int qrow_g = qg + qi * 16;
                if (kmax > qt * 128 + wl * 32 + qi * 16) {     // wave-uniform: crosses diagonal
#pragma unroll
                    for (int nf = 0; nf < 4; nf++) {
                        tm[nf] = -1e30f;
#pragma unroll
                        for (int r = 0; r < 4; r++) {
                            float v = sc[qi][nf][r];
                            if ((kb + nf * 16 + r) > qrow_g) v = -1e30f;
                            ps[nf][r] = v;
                            tm[nf] = fmaxf(tm[nf], v);
                        }
                    }
                } else {
#pragma unroll
                    for (int nf = 0; nf < 4; nf++) {
                        tm[nf] = -1e30f;
#pragma unroll
                        for (int r = 0; r < 4; r++) {
                            float v = sc[qi][nf][r];
                            ps[nf][r] = v;
                            tm[nf] = fmaxf(tm[nf], v);
                        }
                    }
                }
                float tmax = fmaxf(fmaxf(tm[0], tm[1]), fmaxf(tm[2], tm[3]));
                tmax = fmaxf(tmax, __shfl_xor(tmax, 16));
                tmax = fmaxf(tmax, __shfl_xor(tmax, 32));
                const float mprev = m_st[qi];
                if (!__all(tmax - mprev <= 8.0f)) {            // T13 defer-max
                    float mnew = fmaxf(mprev, tmax);
                    float alpha = exp2f(mprev - mnew);
                    l_st[qi] *= alpha;
                    m_st[qi] = mnew;
#pragma unroll
                    for (int r = 0; r < 4; r++) {
                        float ar = __shfl(alpha, quad * 4 + r, 16);
#pragma unroll
                        for (int nd = 0; nd < 8; nd++) o[qi][nd][r] *= ar;
                    }
                }
                const float mcur = m_st[qi];
                float rs[4];
#pragma unroll
                for (int nf = 0; nf < 4; nf++) {
                    rs[nf] = 0.f;
#pragma unroll
                    for (int r = 0; r < 4; r++) {
                        float e = exp2f(ps[nf][r] - mcur);
                        ps[nf][r] = e;
                        rs[nf] += e;
                    }
                }
                float rsum = (rs[0] + rs[1]) + (rs[2] + rs[3]);
                rsum += __shfl_xor(rsum, 16);
                rsum += __shfl_xor(rsum, 32);
                l_st[qi] += rsum;
                const int qrow = qi * 16 + lr;
#pragma unroll
                for (int nf = 0; nf < 4; nf++) {
                    u32 lo = cvt_pk_bf16(ps[nf][0], ps[nf][1]);
                    u32 hi = cvt_pk_bf16(ps[nf][2], ps[nf][3]);
                    int c = (nf * 4 + quad) ^ lr;
                    *(uint2*)&lPw[qrow * 64 + c * 4] = make_uint2(lo, hi);
                }
            }

            // (2) hoist pa reads (same-wave P region, DS-ordered after the writes
            // above) so their lgkm latency drains during the V-wait + barrier.
            bf16x8 pa[2][2];                     // [kf][qi]
#pragma unroll
            for (int kf = 0; kf < 2; kf++) {
#pragma unroll
                for (int qi = 0; qi < 2; qi++) {
                    int c0 = (kf * 8 + quad * 2) ^ lr;
                    int c1 = (kf * 8 + quad * 2 + 1) ^ lr;
                    bf16x4 p0 = *(const bf16x4*)&lPw[(qi * 16 + lr) * 64 + c0 * 4];
                    bf16x4 p1 = *(const bf16x4*)&lPw[(qi * 16 + lr) * 64 + c1 * 4];
                    pa[kf][qi] = __builtin_shufflevector(p0, p1, 0, 1, 2, 3, 4, 5, 6, 7);
                }
            }

            if (t + 1 < niters) asm volatile("s_waitcnt vmcnt(8)" ::: "memory");  // waits V(t); K(t+1),V(t+1) stay
            else                asm volatile("s_waitcnt vmcnt(0)" ::: "memory");
            asm volatile("s_barrier" ::: "memory");

            const u16* vcur = base_g + 16384 + bu * 8192;
            __builtin_amdgcn_s_setprio(1);
#pragma unroll
            for (int kf = 0; kf < 2; kf++) {
#pragma unroll
                for (int nd = 0; nd < 8; nd++) {
                    bf16x8 vv = *(const bf16x8*)&vcur[(nd * 16 + lr) * 64 + (((kf * 4 + quad) ^ (lr & 7)) * 8)];
                    o[0][nd] = __builtin_amdgcn_mfma_f32_16x16x32_bf16(pa[kf][0], vv, o[0][nd], 0, 0, 0);
                    o[1][nd] = __builtin_amdgcn_mfma_f32_16x16x32_bf16(pa[kf][1], vv, o[1][nd], 0, 0, 0);
                }
            }
            __builtin_amdgcn_s_setprio(0);
            // no third barrier: next iter's first barrier seals PV reads
        }

        // ---- in-block merge of the two K-halves ----
        __syncthreads();
        if (grp == 1) {
#pragma unroll
            for (int qi = 0; qi < 2; qi++) {
#pragma unroll
                for (int r = 0; r < 4; r++) {
                    int row = wl * 32 + qi * 16 + quad * 4 + r;
#pragma unroll
                    for (int nd = 0; nd < 8; nd++)
                        mO[row * 128 + nd * 16 + lr] = o[qi][nd][r];
                }
                if (quad == 0) {
                    int rowl = wl * 32 + qi * 16 + lr;
                    mM[rowl * 2]     = m_st[qi];
                    mM[rowl * 2 + 1] = l_st[qi];
                }
            }
        }
        __syncthreads();
        if (grp == 0) {
#pragma unroll
            for (int qi = 0; qi < 2; qi++) {
                int rowl = wl * 32 + qi * 16 + lr;
                float m1 = mM[rowl * 2], l1 = mM[rowl * 2 + 1];
                float M  = fmaxf(m_st[qi], m1);
                float a0 = exp2f(m_st[qi] - M);
                float a1 = exp2f(m1 - M);
                float li = 1.0f / (l_st[qi] * a0 + l1 * a1);
                u16* obase = ob + (size_t)(b * SEQ + qt * 128 + wl * 32 + qi * 16) * 2048 + h * 128;
#pragma unroll
                for (int r = 0; r < 4; r++) {
                    float a0b = __shfl(a0, quad * 4 + r, 16);
                    float a1b = __shfl(a1, quad * 4 + r, 16);
                    float lib = __shfl(li, quad * 4 + r, 16);
                    int row = wl * 32 + qi * 16 + quad * 4 + r;
#pragma unroll
                    for (int nd = 0; nd < 8; nd++) {
                        float val = (o[qi][nd][r] * a0b + mO[row * 128 + nd * 16 + lr] * a1b) * lib;
                        obase[(quad * 4 + r) * 2048 + nd * 16 + lr] = f2bf(val);
                    }
                }
            }
        }
        __syncthreads();   // merge reads done before next phase restages K/V regions
    }
}

extern "C" void kernel_launch(void* const* d_in, const int* in_sizes, int n_in,
                              void* d_out, int out_size, void* d_ws, size_t ws_size,
                              hipStream_t stream) {
    (void)in_sizes; (void)n_in; (void)out_size; (void)ws_size;
    const float* x    = (const float*)d_in[0];
    const float* cosp = (const float*)d_in[1];
    const float* sinp = (const float*)d_in[2];
    const float* wq   = (const float*)d_in[3];
    const float* wk   = (const float*)d_in[4];
    const float* wv   = (const float*)d_in[5];
    const float* wo   = (const float*)d_in[6];
    float* out = (float*)d_out;

    char* ws = (char*)d_ws;
    u16* xb    = (u16*)(ws);                               // 16 MB (reused as ob)
    u16* qkvb  = (u16*)(ws + (size_t)16 * 1024 * 1024);    // 24 MB
    u16* wqkvT = (u16*)(ws + (size_t)40 * 1024 * 1024);    // 12 MB
    u16* woT   = (u16*)(ws + (size_t)52 * 1024 * 1024);    //  8 MB
    u16* vtb   = (u16*)(ws + (size_t)60 * 1024 * 1024);    //  4 MB
    u16* ob    = xb;                                       // alias: xb dead after QKV GEMM

    prep<<<10752, 256, 0, stream>>>(x, wq, wk, wv, wo, xb, wqkvT, woT);
    // QKV GEMM with fused K-RoPE + V-transpose epilogue; grid 768 = 3x256 CUs
    gemm128<true><<<768, 256, 0, stream>>>(xb, wqkvT, (void*)qkvb, 3072, 2048, 24,
                                           cosp, sinp, vtb);
    flash_attn<<<256, 512, 0, stream>>>(qkvb, vtb, cosp, sinp, ob);
    // out-proj; grid 512 = 2x256 CUs
    gemm128<false><<<512, 256, 0, stream>>>(ob, woT, (void*)out, 2048, 2048, 16,
                                            nullptr, nullptr, nullptr);
}

// Round 12
// 300.774 us; speedup vs baseline: 1.0142x; 1.0123x over previous
//
#include <hip/hip_runtime.h>
#include <stdint.h>

#define SEQ 2048
// B=2, DIM=2048, NH=16, NKV=4, HD=128, qkv width = 2048+512+512 = 3072

typedef uint16_t u16;
typedef uint32_t u32;
typedef __attribute__((ext_vector_type(4))) float f32x4;
typedef __attribute__((ext_vector_type(8))) __bf16 bf16x8;
typedef __attribute__((ext_vector_type(4))) __bf16 bf16x4;

__device__ __forceinline__ u16 f2bf(float f) {
    u32 u = __float_as_uint(f);
    u += 0x7FFFu + ((u >> 16) & 1u);   // RNE
    return (u16)(u >> 16);
}
__device__ __forceinline__ float bf2f(u16 h) {
    return __uint_as_float(((u32)h) << 16);
}
// packed f32x2 -> bf16x2 (RNE), 1 VALU instr instead of ~8
__device__ __forceinline__ u32 cvt_pk_bf16(float lo, float hi) {
    u32 r;
    asm("v_cvt_pk_bf16_f32 %0, %1, %2" : "=v"(r) : "v"(lo), "v"(hi));
    return r;
}
__device__ __forceinline__ void async16(const void* g, void* l) {
    auto gp = (__attribute__((address_space(1))) void*)const_cast<void*>(g);
    auto lp = (__attribute__((address_space(3))) void*)l;
    __builtin_amdgcn_global_load_lds(gp, lp, 16, 0, 0);
}

// ------------- prep: x fp32->bf16 (blocks 0..8191) + all 4 weight transposes -------------
// blocks [8192, 10752): tconv over (bx, k0): bx in [0,80), by in [0,32).
__global__ __launch_bounds__(256) void prep(const float* __restrict__ x,
                                            const float* __restrict__ wq,
                                            const float* __restrict__ wk,
                                            const float* __restrict__ wv,
                                            const float* __restrict__ wo,
                                            u16* __restrict__ xb,
                                            u16* __restrict__ wqkvT,
                                            u16* __restrict__ woT) {
    const int bid = blockIdx.x;
    const int tid = threadIdx.x;
    if (bid < 8192) {
        int i = bid * 256 + tid;                 // one float4 per thread
        float4 v = ((const float4*)x)[i];
        ((uint2*)xb)[i] = make_uint2(cvt_pk_bf16(v.x, v.y), cvt_pk_bf16(v.z, v.w));
        return;
    }
    __shared__ float tile[64][65];
    const int tb = bid - 8192;
    const int bx = tb % 80, k0 = (tb / 80) * 64;
    const float* src; u16* dst; int N, n0;
    if (bx < 32)      { src = wq; dst = wqkvT;                        N = 2048; n0 = bx * 64; }
    else if (bx < 40) { src = wk; dst = wqkvT + (size_t)2048 * 2048;  N = 512;  n0 = (bx - 32) * 64; }
    else if (bx < 48) { src = wv; dst = wqkvT + (size_t)2560 * 2048;  N = 512;  n0 = (bx - 40) * 64; }
    else              { src = wo; dst = woT;                          N = 2048; n0 = (bx - 48) * 64; }
#pragma unroll
    for (int p = 0; p < 4; p++) {
        int r = p * 16 + (tid >> 4);
        int c = (tid & 15) * 4;
        float4 v = *(const float4*)&src[(size_t)(k0 + r) * N + n0 + c];
        tile[r][c] = v.x; tile[r][c+1] = v.y; tile[r][c+2] = v.z; tile[r][c+3] = v.w;
    }
    __syncthreads();
#pragma unroll
    for (int p = 0; p < 4; p++) {
        int n = p * 16 + (tid >> 4);
        int kq = (tid & 15) * 4;
        u32 lo = cvt_pk_bf16(tile[kq+0][n], tile[kq+1][n]);
        u32 hi = cvt_pk_bf16(tile[kq+2][n], tile[kq+3][n]);
        *(uint2*)&dst[(size_t)(n0 + n) * 2048 + k0 + kq] = make_uint2(lo, hi);
    }
}

// ---------------- bf16 GEMM, 128x128 tile, SLOTS-slot ring, counted vmcnt ----------------
// r5 structure, ONE barrier per K-tile. SLOTS=3: 48 KB LDS -> 3 blocks/CU resident
// (12 waves/CU; the occupancy lever m114 says drives implicit overlap). SLOTS=4: r10
// control (64 KB, 2 blocks/CU). Ledger (depth SLOTS-1 prefetch): prologue stages tiles
// 0..SLOTS-2, vmcnt((SLOTS-2)*4) = tile 0 landed; iter kt stages kt+SLOTS-1 into the
// slot freed at iter kt-1 (readers lgkm-sealed by that iter's end barrier); steady-state
// end vmcnt((SLOTS-2)*4) = tile kt+1 landed; tail drains to 0.
template <bool FUSE, int SLOTS>
__global__ __launch_bounds__(256, 3) void gemm128(const u16* __restrict__ A,
                                                  const u16* __restrict__ Bt,
                                                  void* __restrict__ Cv,
                                                  int N, int K, int nbx,
                                                  const float* __restrict__ cosp,
                                                  const float* __restrict__ sinp,
                                                  u16* __restrict__ vt) {
    __shared__ u16 lds[SLOTS * 8192];         // SLOTS x (A 4096 + B 4096) u16

    // bijective XCD swizzle (m204)
    const int nwg = gridDim.x;
    const int q = nwg >> 3, r = nwg & 7;
    const int xcd = blockIdx.x & 7, lid = blockIdx.x >> 3;
    const int wg = (xcd < r ? xcd * (q + 1) : r * (q + 1) + (xcd - r) * q) + lid;
    const int by = wg / nbx, bx = wg - by * nbx;
    const int m0 = by * 128, n0 = bx * 128;

    const int tid = threadIdx.x;
    const int w = tid >> 6, l = tid & 63;
    const int lr = l & 15, quad = l >> 4;
    const int wm = (w >> 1) * 64, wn = (w & 1) * 64;
    const int cs = ((quad ^ (lr & 3) ^ ((lr >> 2) & 3)) & 3) * 8;

    const int sr = tid >> 2;
    const int sg = tid & 3;
    const int swz = (sr ^ (sr >> 2)) & 3;
    const u16* aS = A  + (size_t)(m0 + sr) * K + (sg ^ swz) * 8;
    const u16* bS = Bt + (size_t)(n0 + sr) * K + (sg ^ swz) * 8;
    u16* ldA = lds + tid * 8;
    u16* ldB = lds + 4096 + tid * 8;

    f32x4 acc[4][4] = {};
    const int nK = K >> 5;

    auto stage = [&](int kt, int slot) {
        u16* dA = ldA + slot * 8192;
        u16* dB = ldB + slot * 8192;
        const u16* sa = aS + (size_t)kt * 32;
        const u16* sb = bS + (size_t)kt * 32;
        async16(sa, dA);
        async16(sa + (size_t)64 * K, dA + 2048);   // swz(row+64) == swz(row)
        async16(sb, dB);
        async16(sb + (size_t)64 * K, dB + 2048);
    };

#pragma unroll
    for (int s = 0; s < SLOTS - 1; s++) stage(s, s);
    if constexpr (SLOTS == 4)
        asm volatile("s_waitcnt vmcnt(8)" ::: "memory");   // tile 0 landed
    else
        asm volatile("s_waitcnt vmcnt(4)" ::: "memory");   // tile 0 landed
    __builtin_amdgcn_s_barrier();

    int rs = 0, ss = SLOTS - 1;                // read slot kt%SLOTS; stage slot (kt+SLOTS-1)%SLOTS
    for (int kt = 0; kt < nK; ++kt) {
        const u16* As = lds + rs * 8192;
        const u16* Bs = As + 4096;
        bf16x8 af[4], bfr[4];
#pragma unroll
        for (int i = 0; i < 4; i++)
            af[i] = *(const bf16x8*)&As[(wm + i * 16 + lr) * 32 + cs];
#pragma unroll
        for (int i = 0; i < 4; i++)
            bfr[i] = *(const bf16x8*)&Bs[(wn + i * 16 + lr) * 32 + cs];
        if (kt + SLOTS - 1 < nK) stage(kt + SLOTS - 1, ss);   // slot freed last iter
        asm volatile("s_waitcnt lgkmcnt(0)" ::: "memory");
        __builtin_amdgcn_s_setprio(1);
#pragma unroll
        for (int mf = 0; mf < 4; mf++)
#pragma unroll
            for (int nf = 0; nf < 4; nf++)
                acc[mf][nf] = __builtin_amdgcn_mfma_f32_16x16x32_bf16(af[mf], bfr[nf], acc[mf][nf], 0, 0, 0);
        __builtin_amdgcn_s_setprio(0);
        if constexpr (SLOTS == 4) {
            if (kt < nK - 3)       asm volatile("s_waitcnt vmcnt(8)" ::: "memory");
            else if (kt == nK - 3) asm volatile("s_waitcnt vmcnt(4)" ::: "memory");
            else if (kt == nK - 2) asm volatile("s_waitcnt vmcnt(0)" ::: "memory");
        } else {
            if (kt < nK - 2)       asm volatile("s_waitcnt vmcnt(4)" ::: "memory");
            else if (kt == nK - 2) asm volatile("s_waitcnt vmcnt(0)" ::: "memory");
        }
        if (kt < nK - 1) __builtin_amdgcn_s_barrier();   // the ONLY barrier per K-tile
        rs = (rs + 1 == SLOTS) ? 0 : rs + 1;
        ss = (ss + 1 == SLOTS) ? 0 : ss + 1;
    }

    // ---------------- epilogue ----------------
    if constexpr (FUSE) {
        if (n0 >= 2560) {
            // V block: write transposed to vt[(b*4+kh)*128+d][token]
            const int bb = m0 >> 11;
#pragma unroll
            for (int mf = 0; mf < 4; mf++) {
                const int token0 = (m0 + wm + mf * 16 + quad * 4) & (SEQ - 1);
#pragma unroll
                for (int nf = 0; nf < 4; nf++) {
                    int dg = n0 - 2560 + wn + nf * 16 + lr;
                    int kh = dg >> 7, d = dg & 127;
                    u32 lo = cvt_pk_bf16(acc[mf][nf][0], acc[mf][nf][1]);
                    u32 hi = cvt_pk_bf16(acc[mf][nf][2], acc[mf][nf][3]);
                    *(uint2*)&vt[((size_t)((bb * 4 + kh) * 128 + d)) * SEQ + token0] = make_uint2(lo, hi);
                }
            }
        } else if (n0 >= 2048) {
            // K block: RoPE on f32 acc, then bf16 store
            const float sgn = (lr & 1) ? 1.0f : -1.0f;
#pragma unroll
            for (int mf = 0; mf < 4; mf++) {
#pragma unroll
                for (int nf = 0; nf < 4; nf++) {
                    int col = n0 + wn + nf * 16 + lr;
                    int ci = (col & 127) >> 1;
#pragma unroll
                    for (int rr = 0; rr < 4; rr++) {
                        size_t row = (size_t)(m0 + wm + mf * 16 + quad * 4 + rr);
                        int token = (int)row & (SEQ - 1);
                        float v = acc[mf][nf][rr];
                        float ppart = __shfl_xor(v, 1);
                        float c = cosp[token * 64 + ci];
                        float s = sinp[token * 64 + ci];
                        float ov = fmaf(sgn * ppart, s, v * c);
                        ((u16*)Cv)[row * (size_t)N + col] = f2bf(ov);
                    }
                }
            }
        } else {
#pragma unroll
            for (int mf = 0; mf < 4; mf++)
#pragma unroll
                for (int nf = 0; nf < 4; nf++)
#pragma unroll
                    for (int rr = 0; rr < 4; rr++) {
                        size_t row = (size_t)(m0 + wm + mf * 16 + quad * 4 + rr);
                        size_t col = (size_t)(n0 + wn + nf * 16 + lr);
                        ((u16*)Cv)[row * (size_t)N + col] = f2bf(acc[mf][nf][rr]);
                    }
        }
    } else {
#pragma unroll
        for (int mf = 0; mf < 4; mf++)
#pragma unroll
            for (int nf = 0; nf < 4; nf++)
#pragma unroll
                for (int rr = 0; rr < 4; rr++) {
                    size_t row = (size_t)(m0 + wm + mf * 16 + quad * 4 + rr);
                    size_t col = (size_t)(n0 + wn + nf * 16 + lr);
                    ((float*)Cv)[row * (size_t)N + col] = acc[mf][nf][rr];
                }
    }
}

// ---------------- causal GQA flash attention (r11-verified: V-dbuf + early V issue) ----------------
__global__ __launch_bounds__(512, 2) void flash_attn(const u16* __restrict__ qkv,
                                                     const u16* __restrict__ vt,
                                                     const float* __restrict__ cosp,
                                                     const float* __restrict__ sinp,
                                                     u16* __restrict__ ob) {
    __shared__ u16 sh[81920];                    // 160 KB
    const int bidx = blockIdx.x;
    const int xcd   = bidx & 7;
    const int inner = bidx >> 3;
    const int b  = xcd >> 2, kh = xcd & 3;       // (b,kh) constant per XCD
    const int h  = kh * 4 + (inner & 3);
    const int a  = inner >> 2;
    const int tid = threadIdx.x;
    const int w = tid >> 6, lane = tid & 63;
    const int grp = w >> 2, wl = w & 3;
    const int lr = lane & 15, quad = lane >> 4;
    const float qscale = 0.088388347762f * 1.4426950408889634f;   // (1/sqrt(128))*log2(e)

    u16* base_g = sh + grp * 32768;              // kb0 | kb1 | vb0 | vb1 (8192 u16 each)
    u16* lPw = sh + 65536 + w * 2048;            // 32 rows x 64 per wave

    const int tidg = tid & 255;
    const int krow = tidg >> 4;
    const int kchunk = (tidg & 15) ^ krow;
    const int vrow = tidg >> 3;
    const int vchunk = (tidg & 7) ^ (vrow & 7);
    const u16* kRow = qkv + (size_t)b * SEQ * 3072 + 2048 + kh * 128
                    + (size_t)krow * 3072 + kchunk * 8;
    const u16* vRow = vt + (size_t)(b * 4 + kh) * 128 * SEQ
                    + (size_t)vrow * SEQ + vchunk * 8;

    auto stageK = [&](int kt, int buf) {
        u16* d = base_g + buf * 8192 + tidg * 8;
#pragma unroll
        for (int i = 0; i < 4; i++)
            async16(kRow + (size_t)(kt * 64 + i * 16) * 3072, d + i * 2048);
    };
    auto stageV = [&](int kt, int buf) {
        u16* d = base_g + 16384 + buf * 8192 + tidg * 8;
#pragma unroll
        for (int i = 0; i < 4; i++)
            async16(vRow + (size_t)(i * 32) * SEQ + kt * 64, d + i * 2048);
    };

    float* mO = (float*)sh;                      // merge: 128x128 f32 (over grp0 K/V, dead then)
    float* mM = (float*)(sh + 65536);            // merge: 128x(m,l) f32 (over P region, dead then)

    for (int p = 0; p < 2; p++) {
        const int qt = p ? (7 - a) : (8 + a);
        const int niters = p ? (8 - a) : (9 + a);
        const int kt0 = grp * niters;

        stageK(kt0, 0);                          // prologue prefetch hides under Q-RoPE
        stageV(kt0, 0);

        // Q fragments (A-layout) with fused RoPE + scale*log2e
        bf16x8 qf[2][4];
#pragma unroll
        for (int qi = 0; qi < 2; qi++) {
            const int token = qt * 128 + wl * 32 + qi * 16 + lr;
            const u16* qb = qkv + (size_t)(b * SEQ + token) * 3072 + h * 128;
#pragma unroll
            for (int kk = 0; kk < 4; kk++) {
                uint4 raw = *(const uint4*)(qb + kk * 32 + quad * 8);
                u32 rw[4] = {raw.x, raw.y, raw.z, raw.w};
                union { u32 u[4]; bf16x8 v; } fr;
#pragma unroll
                for (int pp = 0; pp < 4; pp++) {
                    int ci = kk * 16 + quad * 4 + pp;
                    float cv = cosp[token * 64 + ci];
                    float sv = sinp[token * 64 + ci];
                    float tr = bf2f((u16)(rw[pp] & 0xFFFFu));
                    float ti = bf2f((u16)(rw[pp] >> 16));
                    fr.u[pp] = cvt_pk_bf16((tr * cv - ti * sv) * qscale,
                                           (tr * sv + ti * cv) * qscale);
                }
                qf[qi][kk] = fr.v;
            }
        }

        f32x4 o[2][8] = {};
        float m_st[2] = {-1e30f, -1e30f};
        float l_st[2] = {0.f, 0.f};
        const int qg = qt * 128 + wl * 32 + lr;

        for (int t = 0; t < niters; t++) {
            const int kt = kt0 + t;
            const int bu = t & 1;
            if (t + 1 < niters) {
                stageK(kt + 1, bu ^ 1);
                asm volatile("s_waitcnt vmcnt(8)" ::: "memory");   // waits exactly K(t)
            } else {
                asm volatile("s_waitcnt vmcnt(4)" ::: "memory");   // waits K(t), leaves V(t)
            }
            asm volatile("s_barrier" ::: "memory");                // also seals PV(t-1) reads

            // issue V(t+1) NOW: vb[bu^1]'s last readers (PV(t-1)) sealed by the
            // barrier above; latency hides under QK + softmax + PV.
            if (t + 1 < niters) stageV(kt + 1, bu ^ 1);

            const u16* kcur = base_g + bu * 8192;
            f32x4 sc[2][4] = {};
            __builtin_amdgcn_s_setprio(1);
#pragma unroll
            for (int nf = 0; nf < 4; nf++) {
#pragma unroll
                for (int kk = 0; kk < 4; kk++) {
                    bf16x8 ak = *(const bf16x8*)&kcur[(nf * 16 + lr) * 128 + (((kk * 4 + quad) ^ lr) * 8)];
                    sc[0][nf] = __builtin_amdgcn_mfma_f32_16x16x32_bf16(ak, qf[0][kk], sc[0][nf], 0, 0, 0);
                    sc[1][nf] = __builtin_amdgcn_mfma_f32_16x16x32_bf16(ak, qf[1][kk], sc[1][nf], 0, 0, 0);
                }
            }
            __builtin_amdgcn_s_setprio(0);

            const int kb = kt * 64 + quad * 4;
            const int kmax = kt * 64 + 63;
#pragma unroll
            for (int qi = 0; qi < 2; qi++) {
                float ps[4][4];
                float tm[4];
                const int qrow_g = qg + qi * 16;
                if (kmax > qt * 128 + wl * 32 + qi * 16) {     // wave-uniform: crosses diagonal
#pragma unroll
                    for (int nf = 0; nf < 4; nf++) {
                        tm[nf] = -1e30f;
#pragma unroll
                        for (int r = 0; r < 4; r++) {
                            float v = sc[qi][nf][r];
                            if ((kb + nf * 16 + r) > qrow_g) v = -1e30f;
                            ps[nf][r] = v;
                            tm[nf] = fmaxf(tm[nf], v);
                        }
                    }
                } else {
#pragma unroll
                    for (int nf = 0; nf < 4; nf++) {
                        tm[nf] = -1e30f;
#pragma unroll
                        for (int r = 0; r < 4; r++) {
                            float v = sc[qi][nf][r];
                            ps[nf][r] = v;
                            tm[nf] = fmaxf(tm[nf], v);
                        }
                    }
                }
                float tmax = fmaxf(fmaxf(tm[0], tm[1]), fmaxf(tm[2], tm[3]));
                tmax = fmaxf(tmax, __shfl_xor(tmax, 16));
                tmax = fmaxf(tmax, __shfl_xor(tmax, 32));
                const float mprev = m_st[qi];
                if (!__all(tmax - mprev <= 8.0f)) {            // T13 defer-max
                    float mnew = fmaxf(mprev, tmax);
                    float alpha = exp2f(mprev - mnew);
                    l_st[qi] *= alpha;
                    m_st[qi] = mnew;
#pragma unroll
                    for (int r = 0; r < 4; r++) {
                        float ar = __shfl(alpha, quad * 4 + r, 16);
#pragma unroll
                        for (int nd = 0; nd < 8; nd++) o[qi][nd][r] *= ar;
                    }
                }
                const float mcur = m_st[qi];
                float rs[4];
#pragma unroll
                for (int nf = 0; nf < 4; nf++) {
                    rs[nf] = 0.f;
#pragma unroll
                    for (int r = 0; r < 4; r++) {
                        float e = exp2f(ps[nf][r] - mcur);
                        ps[nf][r] = e;
                        rs[nf] += e;
                    }
                }
                float rsum = (rs[0] + rs[1]) + (rs[2] + rs[3]);
                rsum += __shfl_xor(rsum, 16);
                rsum += __shfl_xor(rsum, 32);
                l_st[qi] += rsum;
                const int qrow = qi * 16 + lr;
#pragma unroll
                for (int nf = 0; nf < 4; nf++) {
                    u32 lo = cvt_pk_bf16(ps[nf][0], ps[nf][1]);
                    u32 hi = cvt_pk_bf16(ps[nf][2], ps[nf][3]);
                    int c = (nf * 4 + quad) ^ lr;
                    *(uint2*)&lPw[qrow * 64 + c * 4] = make_uint2(lo, hi);
                }
            }

            // hoist pa reads (same-wave P region, DS-ordered after the writes
            // above) so their lgkm latency drains during the V-wait + barrier.
            bf16x8 pa[2][2];                     // [kf][qi]
#pragma unroll
            for (int kf = 0; kf < 2; kf++) {
#pragma unroll
                for (int qi = 0; qi < 2; qi++) {
                    int c0 = (kf * 8 + quad * 2) ^ lr;
                    int c1 = (kf * 8 + quad * 2 + 1) ^ lr;
                    bf16x4 p0 = *(const bf16x4*)&lPw[(qi * 16 + lr) * 64 + c0 * 4];
                    bf16x4 p1 = *(const bf16x4*)&lPw[(qi * 16 + lr) * 64 + c1 * 4];
                    pa[kf][qi] = __builtin_shufflevector(p0, p1, 0, 1, 2, 3, 4, 5, 6, 7);
                }
            }

            if (t + 1 < niters) asm volatile("s_waitcnt vmcnt(8)" ::: "memory");  // waits V(t); K(t+1),V(t+1) stay
            else                asm volatile("s_waitcnt vmcnt(0)" ::: "memory");
            asm volatile("s_barrier" ::: "memory");

            const u16* vcur = base_g + 16384 + bu * 8192;
            __builtin_amdgcn_s_setprio(1);
#pragma unroll
            for (int kf = 0; kf < 2; kf++) {
#pragma unroll
                for (int nd = 0; nd < 8; nd++) {
                    bf16x8 vv = *(const bf16x8*)&vcur[(nd * 16 + lr) * 64 + (((kf * 4 + quad) ^ (lr & 7)) * 8)];
                    o[0][nd] = __builtin_amdgcn_mfma_f32_16x16x32_bf16(pa[kf][0], vv, o[0][nd], 0, 0, 0);
                    o[1][nd] = __builtin_amdgcn_mfma_f32_16x16x32_bf16(pa[kf][1], vv, o[1][nd], 0, 0, 0);
                }
            }
            __builtin_amdgcn_s_setprio(0);
            // no third barrier: next iter's first barrier seals PV reads
        }

        // ---- in-block merge of the two K-halves ----
        __syncthreads();
        if (grp == 1) {
#pragma unroll
            for (int qi = 0; qi < 2; qi++) {
#pragma unroll
                for (int r = 0; r < 4; r++) {
                    int row = wl * 32 + qi * 16 + quad * 4 + r;
#pragma unroll
                    for (int nd = 0; nd < 8; nd++)
                        mO[row * 128 + nd * 16 + lr] = o[qi][nd][r];
                }
                if (quad == 0) {
                    int rowl = wl * 32 + qi * 16 + lr;
                    mM[rowl * 2]     = m_st[qi];
                    mM[rowl * 2 + 1] = l_st[qi];
                }
            }
        }
        __syncthreads();
        if (grp == 0) {
#pragma unroll
            for (int qi = 0; qi < 2; qi++) {
                int rowl = wl * 32 + qi * 16 + lr;
                float m1 = mM[rowl * 2], l1 = mM[rowl * 2 + 1];
                float M  = fmaxf(m_st[qi], m1);
                float a0 = exp2f(m_st[qi] - M);
                float a1 = exp2f(m1 - M);
                float li = 1.0f / (l_st[qi] * a0 + l1 * a1);
                u16* obase = ob + (size_t)(b * SEQ + qt * 128 + wl * 32 + qi * 16) * 2048 + h * 128;
#pragma unroll
                for (int r = 0; r < 4; r++) {
                    float a0b = __shfl(a0, quad * 4 + r, 16);
                    float a1b = __shfl(a1, quad * 4 + r, 16);
                    float lib = __shfl(li, quad * 4 + r, 16);
                    int row = wl * 32 + qi * 16 + quad * 4 + r;
#pragma unroll
                    for (int nd = 0; nd < 8; nd++) {
                        float val = (o[qi][nd][r] * a0b + mO[row * 128 + nd * 16 + lr] * a1b) * lib;
                        obase[(quad * 4 + r) * 2048 + nd * 16 + lr] = f2bf(val);
                    }
                }
            }
        }
        __syncthreads();   // merge reads done before next phase restages K/V regions
    }
}

extern "C" void kernel_launch(void* const* d_in, const int* in_sizes, int n_in,
                              void* d_out, int out_size, void* d_ws, size_t ws_size,
                              hipStream_t stream) {
    (void)in_sizes; (void)n_in; (void)out_size; (void)ws_size;
    const float* x    = (const float*)d_in[0];
    const float* cosp = (const float*)d_in[1];
    const float* sinp = (const float*)d_in[2];
    const float* wq   = (const float*)d_in[3];
    const float* wk   = (const float*)d_in[4];
    const float* wv   = (const float*)d_in[5];
    const float* wo   = (const float*)d_in[6];
    float* out = (float*)d_out;

    char* ws = (char*)d_ws;
    u16* xb    = (u16*)(ws);                               // 16 MB (reused as ob)
    u16* qkvb  = (u16*)(ws + (size_t)16 * 1024 * 1024);    // 24 MB
    u16* wqkvT = (u16*)(ws + (size_t)40 * 1024 * 1024);    // 12 MB
    u16* woT   = (u16*)(ws + (size_t)52 * 1024 * 1024);    //  8 MB
    u16* vtb   = (u16*)(ws + (size_t)60 * 1024 * 1024);    //  4 MB
    u16* ob    = xb;                                       // alias: xb dead after QKV GEMM

    prep<<<10752, 256, 0, stream>>>(x, wq, wk, wv, wo, xb, wqkvT, woT);
    // QKV GEMM: 3-slot ring (48 KB -> 3 blocks/CU), grid 768 = 3x256 CUs
    gemm128<true, 3><<<768, 256, 0, stream>>>(xb, wqkvT, (void*)qkvb, 3072, 2048, 24,
                                              cosp, sinp, vtb);
    flash_attn<<<256, 512, 0, stream>>>(qkvb, vtb, cosp, sinp, ob);
    // out-proj: 4-slot control (64 KB, grid 512 = 2x256 CUs is grid-limited anyway)
    gemm128<false, 4><<<512, 256, 0, stream>>>(ob, woT, (void*)out, 2048, 2048, 16,
                                               nullptr, nullptr, nullptr);
}